// Round 17
// baseline (256.547 us; speedup 1.0000x reference)
//
#include <hip/hip_runtime.h>
#include <cstdint>
#include <cstddef>

#define HIDDEN 1024
#define NH 16
#define NKV 8
#define HD 128
#define SEQ 2048
#define BATCH 2
#define NTOK (BATCH*SEQ)        /* 4096 */

typedef __bf16 bf16x8 __attribute__((ext_vector_type(8)));
typedef float f32x4 __attribute__((ext_vector_type(4)));

__device__ __forceinline__ unsigned short f2bf(float f) {
  unsigned int u = __float_as_uint(f);
  u += 0x7FFFu + ((u >> 16) & 1u);          // round-to-nearest-even
  return (unsigned short)(u >> 16);
}
__device__ __forceinline__ float bf2f(unsigned short h) {
  return __uint_as_float(((unsigned int)h) << 16);
}

#if __has_builtin(__builtin_amdgcn_exp2f)
#define EXP2(x) __builtin_amdgcn_exp2f(x)
#else
#define EXP2(x) exp2f(x)
#endif

// async global->LDS, 16B per lane; LDS dest = uniform base + lane*16
__device__ __forceinline__ void glds16(const unsigned short* g, unsigned short* l) {
  __builtin_amdgcn_global_load_lds(
      (const __attribute__((address_space(1))) unsigned int*)g,
      (__attribute__((address_space(3))) unsigned int*)l, 16, 0, 0);
}

// s_waitcnt immediates (gfx9/CDNA: vmcnt[3:0]+[15:14], exp[6:4], lgkm[11:8])
#define WAIT_VM8()   __builtin_amdgcn_s_waitcnt(0x0F78)  /* vmcnt<=8 */
#define WAIT_VM4()   __builtin_amdgcn_s_waitcnt(0x0F74)  /* vmcnt<=4 */
#define WAIT_VM0()   __builtin_amdgcn_s_waitcnt(0x0F70)  /* vmcnt<=0 */
#define WAIT_LGKM0() __builtin_amdgcn_s_waitcnt(0xC07F)  /* lgkmcnt<=0 */
#define BARRIER()    __builtin_amdgcn_s_barrier()

// adjacent-lane (xor 1) exchange-add via quad_perm [1,0,3,2]
__device__ __forceinline__ float dpp_addx1(float x) {
  int v = __builtin_amdgcn_update_dpp(0, __float_as_int(x), 0xB1, 0xF, 0xF, true);
  return x + __int_as_float(v);
}

// ---- all-weights transpose-convert + hs convert, ONE launch ----
__global__ __launch_bounds__(256) void tcvt_all_kernel(
    const float* __restrict__ Wq, const float* __restrict__ Wk,
    const float* __restrict__ Wv, const float* __restrict__ Wo,
    const float* __restrict__ hs,
    unsigned short* __restrict__ wqkvt, unsigned short* __restrict__ wot,
    unsigned short* __restrict__ hsb) {
  const int i = blockIdx.x;
  const int tx = threadIdx.x, ty = threadIdx.y;
  if (i >= 6144) {                           // hs convert: 1024 blocks x 4096 elems
    const int t = ty*32 + tx;
    const size_t base = (size_t)(i - 6144) * 1024;   // in float4 units
#pragma unroll
    for (int j = 0; j < 4; ++j) {
      const size_t idx = base + j*256 + t;
      float4 v = ((const float4*)hs)[idx];
      ushort4 o;
      o.x = f2bf(v.x); o.y = f2bf(v.y); o.z = f2bf(v.z); o.w = f2bf(v.w);
      ((ushort4*)hsb)[idx] = o;
    }
    return;
  }
  __shared__ float tl[32][33];
  const float* src; unsigned short* dst; int R, C, r0, c0;
  if (i < 2048)      { int l = i;        src = Wq; dst = wqkvt;                      R = 1024; C = 2048; r0 = (l & 31)*32; c0 = (l >> 5)*32; }
  else if (i < 3072) { int l = i - 2048; src = Wk; dst = wqkvt + (size_t)2048*1024;  R = 1024; C = 1024; r0 = (l & 31)*32; c0 = (l >> 5)*32; }
  else if (i < 4096) { int l = i - 3072; src = Wv; dst = wqkvt + (size_t)3072*1024;  R = 1024; C = 1024; r0 = (l & 31)*32; c0 = (l >> 5)*32; }
  else               { int l = i - 4096; src = Wo; dst = wot;                        R = 2048; C = 1024; r0 = (l & 63)*32; c0 = (l >> 6)*32; }
#pragma unroll
  for (int k = 0; k < 4; ++k)
    tl[ty + 8*k][tx] = src[(size_t)(r0 + ty + 8*k)*C + c0 + tx];
  __syncthreads();
#pragma unroll
  for (int k = 0; k < 4; ++k)
    dst[(size_t)(c0 + ty + 8*k)*R + r0 + tx] = f2bf(tl[tx][ty + 8*k]);
}

// -------- QKV GEMM (128x128, BK=64, async dbuf) + fused norm/rope/vtrans --------
// R12: vt8 written in kappa-permuted kv order so the attn PV B-fragment (P^T)
// needs NO cross-lane repack.
// R16: ftile stride 132 (2-way spill, 8-way rmsnorm; was 136 = 4/16-way).
__global__ __launch_bounds__(256) void gemm_qkv_fused_kernel(
    const unsigned short* __restrict__ A,      // hs bf16 [4096][1024]
    const unsigned short* __restrict__ Bt,     // wqkvt bf16 [4096][1024]
    const float* __restrict__ qw, const float* __restrict__ kw,
    const int* __restrict__ pos_ids,
    unsigned short* __restrict__ q_l,
    unsigned short* __restrict__ k_l,
    unsigned short* __restrict__ vt8) {
  constexpr int BM = 128, BK = 64, K = 1024, NIT = K/BK;
  constexpr int FS = 132;                      // ftile row stride (fp32 words)
  __shared__ __align__(16) char smem[70144];   // 68.5 KB -> 2 blocks/CU
  unsigned short* As0 = (unsigned short*)smem;           // 2 x 16 KB
  unsigned short* Bs0 = (unsigned short*)(smem + 32768); // 2 x 16 KB
  float* ftile = (float*)smem;                           // 128 x 132 fp32 (67.6 KB)
  float* rinv  = (float*)(smem + 69632);                 // 128 fp32

  const int t = threadIdx.x, lane = t & 63, w = t >> 6;
  const int l15 = lane & 15, l4 = lane >> 4;
  const int wr = (w >> 1)*64, wc = (w & 1)*64;
  const int m0 = blockIdx.x * BM, n0 = blockIdx.y * 128;
  const unsigned short* Ab = A + (size_t)m0*K;
  const unsigned short* Bb = Bt + (size_t)n0*K;

  const f32x4 vzero = {0.f, 0.f, 0.f, 0.f};
  f32x4 acc[4][4];
#pragma unroll
  for (int i = 0; i < 4; ++i)
#pragma unroll
    for (int j = 0; j < 4; ++j) acc[i][j] = vzero;

#pragma unroll
  for (int i = 0; i < 4; ++i) {
    const int c = (w*4 + i)*64 + lane;
    glds16(Ab + (size_t)(c >> 3)*K + (c & 7)*8, As0 + (size_t)(w*4 + i)*512);
  }
#pragma unroll
  for (int i = 0; i < 4; ++i) {
    const int c = (w*4 + i)*64 + lane;
    glds16(Bb + (size_t)(c >> 3)*K + (c & 7)*8, Bs0 + (size_t)(w*4 + i)*512);
  }

  for (int kb = 0; kb < NIT; ++kb) {
    const int cur = kb & 1;
    WAIT_LGKM0(); BARRIER();
    if (kb + 1 < NIT) {
      const int kn = (kb + 1) * BK;
      const int nb = (cur^1)*8192;
#pragma unroll
      for (int i = 0; i < 4; ++i) {
        const int c = (w*4 + i)*64 + lane;
        glds16(Ab + (size_t)(c >> 3)*K + kn + (c & 7)*8, As0 + nb + (size_t)(w*4 + i)*512);
      }
#pragma unroll
      for (int i = 0; i < 4; ++i) {
        const int c = (w*4 + i)*64 + lane;
        glds16(Bb + (size_t)(c >> 3)*K + kn + (c & 7)*8, Bs0 + nb + (size_t)(w*4 + i)*512);
      }
      WAIT_VM8();
    } else {
      WAIT_VM0();
    }
    BARRIER();

    const unsigned short* Ac = As0 + cur*8192;
    const unsigned short* Bc = Bs0 + cur*8192;
#pragma unroll
    for (int kk = 0; kk < 2; ++kk) {
      const int kc = kk*4 + l4;
      bf16x8 af[4], bfr[4];
#pragma unroll
      for (int i = 0; i < 4; ++i) {
        int m = wr + i*16 + l15;
        af[i] = *(const bf16x8*)(Ac + ((size_t)m*8 + kc)*8);
      }
#pragma unroll
      for (int j = 0; j < 4; ++j) {
        int n = wc + j*16 + l15;
        bfr[j] = *(const bf16x8*)(Bc + ((size_t)n*8 + kc)*8);
      }
#pragma unroll
      for (int i = 0; i < 4; ++i)
#pragma unroll
        for (int j = 0; j < 4; ++j)
          acc[i][j] = __builtin_amdgcn_mfma_f32_16x16x32_bf16(af[i], bfr[j], acc[i][j], 0, 0, 0);
    }
  }

  // ---- epilogue: spill C-tile to LDS fp32 [128][FS] ----
  WAIT_LGKM0(); BARRIER();
#pragma unroll
  for (int i = 0; i < 4; ++i)
#pragma unroll
    for (int j = 0; j < 4; ++j)
#pragma unroll
      for (int r = 0; r < 4; ++r) {
        const int row = wr + i*16 + l4*4 + r;
        const int col = wc + j*16 + l15;
        ftile[row*FS + col] = acc[i][j][r];
      }
  WAIT_LGKM0(); BARRIER();

  const int ny = n0 >> 7;                    // 0..15 q-head, 16..23 k-head, 24..31 v-head
  const int S0 = m0 & (SEQ-1);
  const int bb = m0 >> 11;

  if (ny < 24) {
    const bool isQ = ny < 16;
    {
      const int row = t >> 1, h2 = t & 1;
      const float* fr = ftile + row*FS + h2*64;
      float ssq = 0.f;
#pragma unroll
      for (int c = 0; c < 16; ++c) {
        float4 v = *(const float4*)(fr + 4*c);
        ssq += v.x*v.x + v.y*v.y + v.z*v.z + v.w*v.w;
      }
      ssq = dpp_addx1(ssq);
      if (h2 == 0) rinv[row] = rsqrtf(ssq*(1.0f/128.0f) + 1e-6f);
    }
    WAIT_LGKM0(); BARRIER();
    const float* wgt = isQ ? qw : kw;
    const int d = t & 127, rh = t >> 7;
    const float wd = wgt[d];
    const float w2 = wgt[d ^ 64];
    const float sgn = (d < 64) ? -1.f : 1.f;
    const float sOut = isQ ? 0.12751744f : 1.f;     // (1/sqrt(128))*log2(e) folded into q
    const float invf = exp2f(-(float)(d & 63) * 0.31143075889569023f);
    const int pos0 = pos_ids[S0 + rh*64];
    float cs, sn, dc, dsn;
    __sincosf((float)pos0 * invf, &sn, &cs);
    __sincosf(invf, &dsn, &dc);
    const int head = isQ ? ny : (ny - 16);
    unsigned short* dstb = isQ ? (q_l + ((size_t)(bb*NH + head)*SEQ + S0)*HD)
                               : (k_l + ((size_t)(bb*NKV + head)*SEQ + S0)*HD);
#pragma unroll 4
    for (int k = 0; k < 64; ++k) {
      const int row = rh*64 + k;
      const float r  = rinv[row];
      const float x1 = ftile[row*FS + d];
      const float x2 = ftile[row*FS + (d ^ 64)];
      const float y1 = x1*r*wd, y2 = x2*r*w2;
      const float o  = (y1*cs + sgn*(y2*sn)) * sOut;
      dstb[(size_t)row*HD + d] = f2bf(o);
      const float c2 = cs*dc - sn*dsn;       // rotate: pos -> pos+1
      sn = sn*dc + cs*dsn; cs = c2;
    }
  } else {
    // V-epilogue: kappa-permuted store. Slot (slice sl, elem s8) holds
    // C-row = blk*64 + s2*32 + e2*16 + s1*8 + s0*4 + e1*2 + e0.
    const int vh = ny - 24;
    unsigned short* vb = vt8 + (size_t)(bb*NKV + vh)*HD*SEQ;
    const int d = t & 127, sbh = t >> 7;
#pragma unroll
    for (int sb = 0; sb < 8; ++sb) {
      const int sl = sbh*8 + sb;
      const int blk = sl >> 3, s = sl & 7;
      const int base_r = blk*64 + ((s>>2)<<5) + (((s>>1)&1)<<3) + ((s&1)<<2);
      union { unsigned short u[8]; uint4 q; } pk;
#pragma unroll
      for (int s8 = 0; s8 < 8; ++s8) {
        const int row = base_r + ((s8>>2)<<4) + (((s8>>1)&1)<<1) + (s8&1);
        pk.u[s8] = f2bf(ftile[row*FS + d]);
      }
      *(uint4*)(vb + ((size_t)((S0 >> 3) + sl)*128 + d)*8) = pk.q;
    }
  }
}

// ------------- bf16 GEMM (out-proj): 128x128 tile, fp32 out -------------
__global__ __launch_bounds__(256) void gemm_out_kernel(
    const unsigned short* __restrict__ A,
    const unsigned short* __restrict__ Bt,
    float* __restrict__ Cout, int M, int N, int K) {
  constexpr int BK = 64;
  __shared__ unsigned short As[2][128*BK];   // 2 x 16 KB
  __shared__ unsigned short Bs[2][128*BK];   // 2 x 16 KB  -> 64 KB, 2 blocks/CU
  const int t = threadIdx.x, lane = t & 63, w = t >> 6;
  const int l15 = lane & 15, l4 = lane >> 4;
  const int wr = (w >> 1)*64, wc = (w & 1)*64;
  const int m0 = blockIdx.y * 128, n0 = blockIdx.x * 128;
  const unsigned short* Ab = A + (size_t)m0*K;
  const unsigned short* Bb = Bt + (size_t)n0*K;

  const f32x4 vzero = {0.f, 0.f, 0.f, 0.f};
  f32x4 acc[4][4];
#pragma unroll
  for (int i = 0; i < 4; ++i)
#pragma unroll
    for (int j = 0; j < 4; ++j) acc[i][j] = vzero;

  const int NIT = K / BK;
#pragma unroll
  for (int i = 0; i < 4; ++i) {
    const int c = (w*4 + i)*64 + lane;
    glds16(Ab + (size_t)(c >> 3)*K + (c & 7)*8, &As[0][(size_t)(w*4 + i)*512]);
  }
#pragma unroll
  for (int i = 0; i < 4; ++i) {
    const int c = (w*4 + i)*64 + lane;
    glds16(Bb + (size_t)(c >> 3)*K + (c & 7)*8, &Bs[0][(size_t)(w*4 + i)*512]);
  }

  for (int kb = 0; kb < NIT; ++kb) {
    const int cur = kb & 1;
    WAIT_LGKM0(); BARRIER();
    if (kb + 1 < NIT) {
      const int kn = (kb + 1) * BK;
#pragma unroll
      for (int i = 0; i < 4; ++i) {
        const int c = (w*4 + i)*64 + lane;
        glds16(Ab + (size_t)(c >> 3)*K + kn + (c & 7)*8, &As[cur^1][(size_t)(w*4 + i)*512]);
      }
#pragma unroll
      for (int i = 0; i < 4; ++i) {
        const int c = (w*4 + i)*64 + lane;
        glds16(Bb + (size_t)(c >> 3)*K + kn + (c & 7)*8, &Bs[cur^1][(size_t)(w*4 + i)*512]);
      }
      WAIT_VM8();
    } else {
      WAIT_VM0();
    }
    BARRIER();

#pragma unroll
    for (int kk = 0; kk < 2; ++kk) {
      const int kc = kk*4 + l4;
      bf16x8 af[4], bfr[4];
#pragma unroll
      for (int i = 0; i < 4; ++i) {
        int m = wr + i*16 + l15;
        af[i] = *(const bf16x8*)(&As[cur][((size_t)m*8 + kc)*8]);
      }
#pragma unroll
      for (int j = 0; j < 4; ++j) {
        int n = wc + j*16 + l15;
        bfr[j] = *(const bf16x8*)(&Bs[cur][((size_t)n*8 + kc)*8]);
      }
#pragma unroll
      for (int i = 0; i < 4; ++i)
#pragma unroll
        for (int j = 0; j < 4; ++j)
          acc[i][j] = __builtin_amdgcn_mfma_f32_16x16x32_bf16(af[i], bfr[j], acc[i][j], 0, 0, 0);
    }
  }
#pragma unroll
  for (int i = 0; i < 4; ++i)
#pragma unroll
    for (int j = 0; j < 4; ++j)
#pragma unroll
      for (int r = 0; r < 4; ++r) {
        int row = m0 + wr + i*16 + l4*4 + r;
        int col = n0 + wc + j*16 + l15;
        Cout[(size_t)row*N + col] = acc[i][j][r];
      }
}

// ------------- Flash attention, causal, GQA, KV-SPLIT -------------
// R14 memory config (proven: compulsory FETCH, 2 blocks/CU, dbuf K+V).
// R17: (a) exp-split — mask+exp j=0,1 before PV(kk=0); j=2,3 AFTER the PV0
// MFMA cluster so the trans-pipe exps execute while the matrix pipe crunches
// PV0 (wave issues MFMA then keeps issuing independent trans ops).
// (b) lrun via ones-MFMA: oextra[i] = mfma(ones, pb[i], .) — every C row
// holds sum_k P[k][q]; kills 32 VALU adds/iter + the epilogue shfl pair, and
// normalization now sums the SAME bf16-quantized P that feeds O.
__global__ __launch_bounds__(256, 2) void attn_kernel(
    const unsigned short* __restrict__ q_l,
    const unsigned short* __restrict__ k_l,
    const unsigned short* __restrict__ vt8,
    unsigned short* __restrict__ o_part,   // [2][B][NH][SEQ][HD] bf16
    float* __restrict__ l_part) {          // [2][B][NH][SEQ] fp32
  __shared__ __align__(16) char smem[65536];
  unsigned short* Ks0  = (unsigned short*)smem;            // 2 x 16 KB dbuf
  unsigned short* Vts0 = (unsigned short*)(smem + 32768);  // 2 x 16 KB dbuf

  const int t = threadIdx.x;
  const int lane = t & 63;
  const int w = t >> 6;
  const int l15 = lane & 15, l4 = lane >> 4;
  const int hb = blockIdx.x;                 // h + 16*b (fast dim: K/V L2 share)
  const int h = hb & 15, b = hb >> 4;
  const int y = blockIdx.y;                  // 0..31
  const int qt = 15 - (y >> 1);              // longest first
  const int half = y & 1;
  const int kvh = h >> 1;
  const int q0 = qt * 128;
  const int kt0 = half ? (qt + 1) : 0;
  const int kt1 = half ? (2*qt + 2) : (qt + 1);

  const unsigned short* Kg = k_l + ((size_t)(b*NKV + kvh)*SEQ)*HD;
  const unsigned short* Vg = vt8 + (size_t)(b*NKV + kvh)*HD*SEQ;
  const unsigned short* Qbase = q_l + ((size_t)(b*NH + h)*SEQ)*HD;

  const f32x4 vzero = {0.f,0.f,0.f,0.f};
  union { unsigned int u[4]; bf16x8 v; } vones;
#pragma unroll
  for (int i = 0; i < 4; ++i) vones.u[i] = 0x3F803F80u;   // bf16 1.0 x8

  // Q fragments in registers (already scaled by 1/sqrt(d)*log2e)
  bf16x8 qf[2][4];
#pragma unroll
  for (int i = 0; i < 2; ++i) {
    const int row = q0 + w*32 + i*16 + l15;
    const unsigned short* Qp = Qbase + (size_t)row*HD;
#pragma unroll
    for (int kk = 0; kk < 4; ++kk)
      qf[i][kk] = *(const bf16x8*)(Qp + kk*32 + l4*8);
  }

  f32x4 oacc[2][8];                          // O^T: [q-subtile][d-tile]
#pragma unroll
  for (int i = 0; i < 2; ++i)
#pragma unroll
    for (int jd = 0; jd < 8; ++jd) oacc[i][jd] = vzero;
  f32x4 oextra[2];                           // row-sum accumulator (ones-MFMA)
#pragma unroll
  for (int i = 0; i < 2; ++i) oextra[i] = vzero;

  // prologue: issue K(kt0)+V(kt0) into buf 0 (8 loads/wave, R1 pattern)
  {
    const int k00 = kt0 * 64;
#pragma unroll
    for (int i = 0; i < 4; ++i) {            // K tile
      const int kc = w*4 + i;
      const int m = lane ^ (kc & 7);
      glds16(Kg + (size_t)(k00 + m)*HD + kc*8, Ks0 + (size_t)kc*64*8);
    }
#pragma unroll
    for (int i = 0; i < 4; ++i) {            // V tile (kappa-permuted vt8)
      const int id = w*4 + i;
      const int skc = id >> 1, hh = id & 1;
      const int d = (hh*64 + lane) ^ skc;
      glds16(Vg + ((size_t)((k00 >> 3) + skc)*128 + d)*8, Vts0 + (size_t)(skc*128 + hh*64)*8);
    }
  }

#pragma unroll 1
  for (int kt = kt0; kt < kt1; ++kt) {
    const int cur = (kt - kt0) & 1;
    const int k0 = kt * 64;
    WAIT_LGKM0(); BARRIER();                 // all waves done reading buf cur^1
    if (kt + 1 < kt1) {                      // prefetch kt+1 into buf cur^1
      const int kn = k0 + 64;
      unsigned short* Ksn  = Ks0  + (cur^1)*8192;
      unsigned short* Vtsn = Vts0 + (cur^1)*8192;
#pragma unroll
      for (int i = 0; i < 4; ++i) {
        const int kc = w*4 + i;
        const int m = lane ^ (kc & 7);
        glds16(Kg + (size_t)(kn + m)*HD + kc*8, Ksn + (size_t)kc*64*8);
      }
#pragma unroll
      for (int i = 0; i < 4; ++i) {
        const int id = w*4 + i;
        const int skc = id >> 1, hh = id & 1;
        const int d = (hh*64 + lane) ^ skc;
        glds16(Vg + ((size_t)((kn >> 3) + skc)*128 + d)*8, Vtsn + (size_t)(skc*128 + hh*64)*8);
      }
      WAIT_VM8();                             // drain only cur's 8 loads
    } else {
      WAIT_VM0();
    }
    BARRIER();                                // buf cur fully staged

    const unsigned short* KsC  = Ks0  + cur*8192;
    const unsigned short* VtsC = Vts0 + cur*8192;

    // S^T = K Q^T (lane: q = l15 within subtile, kv = j*16 + l4*4 + r)
    f32x4 sacc[4][2];
#pragma unroll
    for (int j = 0; j < 4; ++j)
#pragma unroll
      for (int i = 0; i < 2; ++i) sacc[j][i] = vzero;
    __builtin_amdgcn_s_setprio(1);
#pragma unroll
    for (int kk = 0; kk < 4; ++kk) {
      const int kc = kk*4 + l4;
      bf16x8 kb[4];
#pragma unroll
      for (int j = 0; j < 4; ++j) {
        int n = j*16 + l15;
        kb[j] = *(const bf16x8*)(KsC + ((size_t)kc*64 + (n ^ (kc & 7)))*8);
      }
#pragma unroll
      for (int j = 0; j < 4; ++j)
#pragma unroll
        for (int i = 0; i < 2; ++i)
          sacc[j][i] = __builtin_amdgcn_mfma_f32_16x16x32_bf16(kb[j], qf[i][kk], sacc[j][i], 0,0,0);
    }
    __builtin_amdgcn_s_setprio(0);

    const bool diag = (kt >= 2*qt);
    // mask + exp2, j = 0,1 only (feeds PV kk=0)
#pragma unroll
    for (int j = 0; j < 2; ++j)
#pragma unroll
      for (int i = 0; i < 2; ++i)
#pragma unroll
        for (int r = 0; r < 4; ++r) {
          float sv = sacc[j][i][r];
          if (diag) {
            const int kvg = k0 + j*16 + l4*4 + r;
            const int qg  = q0 + w*32 + i*16 + l15;
            sv = (kvg > qg) ? -INFINITY : sv;
          }
          sacc[j][i][r] = EXP2(sv);
        }

    // PV kk=0 (uses sacc[0],[1]); j=2,3 exps issued right after the MFMA
    // cluster so they run on the trans pipe under PV0.
    {
      union { unsigned int u[4]; bf16x8 v; } pb[2];
#pragma unroll
      for (int i = 0; i < 2; ++i) {
        const f32x4 t0 = sacc[0][i], t1 = sacc[1][i];
        pb[i].u[0] = (__float_as_uint(t0[0]) >> 16) | (__float_as_uint(t0[1]) & 0xFFFF0000u);
        pb[i].u[1] = (__float_as_uint(t0[2]) >> 16) | (__float_as_uint(t0[3]) & 0xFFFF0000u);
        pb[i].u[2] = (__float_as_uint(t1[0]) >> 16) | (__float_as_uint(t1[1]) & 0xFFFF0000u);
        pb[i].u[3] = (__float_as_uint(t1[2]) >> 16) | (__float_as_uint(t1[3]) & 0xFFFF0000u);
      }
      const int s = l4;
      __builtin_amdgcn_s_setprio(1);
#pragma unroll
      for (int td = 0; td < 8; ++td) {
        const int dd = td*16 + l15;
        bf16x8 va = *(const bf16x8*)(VtsC + ((size_t)s*128 + (dd ^ s))*8);
#pragma unroll
        for (int i = 0; i < 2; ++i)
          oacc[i][td] = __builtin_amdgcn_mfma_f32_16x16x32_bf16(va, pb[i].v, oacc[i][td], 0,0,0);
      }
#pragma unroll
      for (int i = 0; i < 2; ++i)
        oextra[i] = __builtin_amdgcn_mfma_f32_16x16x32_bf16(vones.v, pb[i].v, oextra[i], 0,0,0);
      __builtin_amdgcn_s_setprio(0);

      // mask + exp2, j = 2,3 (overlaps PV0 on the trans pipe)
#pragma unroll
      for (int j = 2; j < 4; ++j)
#pragma unroll
        for (int i = 0; i < 2; ++i)
#pragma unroll
          for (int r = 0; r < 4; ++r) {
            float sv = sacc[j][i][r];
            if (diag) {
              const int kvg = k0 + j*16 + l4*4 + r;
              const int qg  = q0 + w*32 + i*16 + l15;
              sv = (kvg > qg) ? -INFINITY : sv;
            }
            sacc[j][i][r] = EXP2(sv);
          }
    }

    // PV kk=1 (uses sacc[2],[3])
    {
      union { unsigned int u[4]; bf16x8 v; } pb[2];
#pragma unroll
      for (int i = 0; i < 2; ++i) {
        const f32x4 t0 = sacc[2][i], t1 = sacc[3][i];
        pb[i].u[0] = (__float_as_uint(t0[0]) >> 16) | (__float_as_uint(t0[1]) & 0xFFFF0000u);
        pb[i].u[1] = (__float_as_uint(t0[2]) >> 16) | (__float_as_uint(t0[3]) & 0xFFFF0000u);
        pb[i].u[2] = (__float_as_uint(t1[0]) >> 16) | (__float_as_uint(t1[1]) & 0xFFFF0000u);
        pb[i].u[3] = (__float_as_uint(t1[2]) >> 16) | (__float_as_uint(t1[3]) & 0xFFFF0000u);
      }
      const int s = 4 + l4;
      __builtin_amdgcn_s_setprio(1);
#pragma unroll
      for (int td = 0; td < 8; ++td) {
        const int dd = td*16 + l15;
        bf16x8 va = *(const bf16x8*)(VtsC + ((size_t)s*128 + (dd ^ s))*8);
#pragma unroll
        for (int i = 0; i < 2; ++i)
          oacc[i][td] = __builtin_amdgcn_mfma_f32_16x16x32_bf16(va, pb[i].v, oacc[i][td], 0,0,0);
      }
#pragma unroll
      for (int i = 0; i < 2; ++i)
        oextra[i] = __builtin_amdgcn_mfma_f32_16x16x32_bf16(vones.v, pb[i].v, oextra[i], 0,0,0);
      __builtin_amdgcn_s_setprio(0);
    }
  }

  // epilogue: lane already holds the full row sum in oextra (all r equal);
  // normalize, store O^T. Fully-masked rows -> sum 0 -> store zeros.
  unsigned short* ob = o_part + ((size_t)half*BATCH*NH*SEQ + (size_t)(b*NH + h)*SEQ)*HD;
  float* lb = l_part + (size_t)half*BATCH*NH*SEQ + (size_t)(b*NH + h)*SEQ;
#pragma unroll
  for (int i = 0; i < 2; ++i) {
    const float lsum = oextra[i][0];
    const float inv = (lsum > 0.f) ? 1.0f / lsum : 0.f;
    const int row = q0 + w*32 + i*16 + l15;
    if (l4 == 0) lb[row] = lsum;
#pragma unroll
    for (int td = 0; td < 8; ++td) {
      union { unsigned int u[2]; uint2 q; } pk;
      const float v0 = oacc[i][td][0]*inv, v1 = oacc[i][td][1]*inv;
      const float v2 = oacc[i][td][2]*inv, v3 = oacc[i][td][3]*inv;
      pk.u[0] = (unsigned int)f2bf(v0) | ((unsigned int)f2bf(v1) << 16);
      pk.u[1] = (unsigned int)f2bf(v2) | ((unsigned int)f2bf(v3) << 16);
      *(uint2*)(ob + (size_t)row*HD + td*16 + l4*4) = pk.q;
    }
  }
}

// ------------- combine: attn_o = (la*Oa + lb*Ob) / (la+lb) -------------
__global__ __launch_bounds__(256) void combine_kernel(
    const unsigned short* __restrict__ o_part,  // [2][B*NH*SEQ][HD] bf16
    const float* __restrict__ l_part,           // [2][B*NH*SEQ] fp32
    unsigned short* __restrict__ attn_o) {      // [B][SEQ][NH*HD] bf16
  const int tid = blockIdx.x * 256 + threadIdx.x;  // 1,048,576 threads
  const int d8 = tid & 15;                    // 16 chunks of 8 d
  const int row = tid >> 4;                   // (b*NH+h)*SEQ + s
  const int s = row & (SEQ-1);
  const int bh = row >> 11;
  const int h = bh & 15, b = bh >> 4;
  const float la = l_part[row];
  const float lbv = l_part[BATCH*NH*SEQ + row];
  const float inv = 1.f / (la + lbv);
  const float wa = la * inv, wb = lbv * inv;
  const unsigned short* pa = o_part + (size_t)row*HD + d8*8;
  const unsigned short* pb = pa + (size_t)BATCH*NH*SEQ*HD;
  uint4 ua = *(const uint4*)pa;
  uint4 ub = *(const uint4*)pb;
  const unsigned short* ea = (const unsigned short*)&ua;
  const unsigned short* eb = (const unsigned short*)&ub;
  union { unsigned short u[8]; uint4 q; } o;
#pragma unroll
  for (int k = 0; k < 8; ++k)
    o.u[k] = f2bf(bf2f(ea[k])*wa + bf2f(eb[k])*wb);
  *(uint4*)(attn_o + ((size_t)(b*SEQ + s)*(NH*HD)) + h*HD + d8*8) = o.q;
}

extern "C" void kernel_launch(void* const* d_in, const int* in_sizes, int n_in,
                              void* d_out, int out_size, void* d_ws, size_t ws_size,
                              hipStream_t stream) {
  const float* hs = (const float*)d_in[0];
  const int* pos  = (const int*)d_in[1];
  const float* Wq = (const float*)d_in[2];
  const float* Wk = (const float*)d_in[3];
  const float* Wv = (const float*)d_in[4];
  const float* Wo = (const float*)d_in[5];
  const float* qw = (const float*)d_in[6];
  const float* kw = (const float*)d_in[7];
  float* out = (float*)d_out;
  char* ws = (char*)d_ws;

  unsigned short* attn_o = (unsigned short*)(ws + 0);                    // 16 MB
  unsigned short* wot    = (unsigned short*)(ws + ((size_t)16 << 20));   // 4 MB
  unsigned short* q_l    = (unsigned short*)(ws + ((size_t)20 << 20));   // 16 MB
  unsigned short* k_l    = (unsigned short*)(ws + ((size_t)36 << 20));   // 8 MB
  unsigned short* vt8    = (unsigned short*)(ws + ((size_t)44 << 20));   // 8 MB
  unsigned short* o_part = (unsigned short*)(ws + ((size_t)52 << 20));   // 32 MB
  unsigned short* hsb    = (unsigned short*)(ws + ((size_t)52 << 20));   // 8 MB (alias)
  unsigned short* wqkvt  = (unsigned short*)(ws + ((size_t)60 << 20));   // 8 MB (alias)
  float*          l_part = (float*)(ws + ((size_t)84 << 20));            // 512 KB

  // 1. all converts in one launch (weights transpose-convert + hs convert)
  tcvt_all_kernel<<<dim3(7168), dim3(32, 8), 0, stream>>>(Wq, Wk, Wv, Wo, hs, wqkvt, wot, hsb);
  // 2. QKV projection + fused RMSNorm/RoPE/V-transpose epilogue (kappa-permuted vt8)
  gemm_qkv_fused_kernel<<<dim3(32, 32), dim3(256), 0, stream>>>(hsb, wqkvt, qw, kw, pos, q_l, k_l, vt8);
  // 3. flash attention: R14 config + exp-split interleave + ones-MFMA row sums
  attn_kernel<<<dim3(32, 32), dim3(256), 0, stream>>>(q_l, k_l, vt8, o_part, l_part);
  // 3b. combine partials -> attn_o
  combine_kernel<<<dim3(4096), dim3(256), 0, stream>>>(o_part, l_part, attn_o);
  // 4. output projection: 128x128 tiles, grid (N/128=8, M/128=32) = 256 blocks
  gemm_out_kernel<<<dim3(8, 32), dim3(256), 0, stream>>>(attn_o, wot, out, 4096, 1024, 2048);
}

// Round 18
// 236.686 us; speedup vs baseline: 1.0839x; 1.0839x over previous
//
#include <hip/hip_runtime.h>
#include <cstdint>
#include <cstddef>

#define HIDDEN 1024
#define NH 16
#define NKV 8
#define HD 128
#define SEQ 2048
#define BATCH 2
#define NTOK (BATCH*SEQ)        /* 4096 */

typedef __bf16 bf16x8 __attribute__((ext_vector_type(8)));
typedef float f32x4 __attribute__((ext_vector_type(4)));

__device__ __forceinline__ unsigned short f2bf(float f) {
  unsigned int u = __float_as_uint(f);
  u += 0x7FFFu + ((u >> 16) & 1u);          // round-to-nearest-even
  return (unsigned short)(u >> 16);
}
__device__ __forceinline__ float bf2f(unsigned short h) {
  return __uint_as_float(((unsigned int)h) << 16);
}

#if __has_builtin(__builtin_amdgcn_exp2f)
#define EXP2(x) __builtin_amdgcn_exp2f(x)
#else
#define EXP2(x) exp2f(x)
#endif

// async global->LDS, 16B per lane; LDS dest = uniform base + lane*16
__device__ __forceinline__ void glds16(const unsigned short* g, unsigned short* l) {
  __builtin_amdgcn_global_load_lds(
      (const __attribute__((address_space(1))) unsigned int*)g,
      (__attribute__((address_space(3))) unsigned int*)l, 16, 0, 0);
}

// s_waitcnt immediates (gfx9/CDNA: vmcnt[3:0]+[15:14], exp[6:4], lgkm[11:8])
#define WAIT_VM8()   __builtin_amdgcn_s_waitcnt(0x0F78)  /* vmcnt<=8 */
#define WAIT_VM4()   __builtin_amdgcn_s_waitcnt(0x0F74)  /* vmcnt<=4 */
#define WAIT_VM0()   __builtin_amdgcn_s_waitcnt(0x0F70)  /* vmcnt<=0 */
#define WAIT_LGKM0() __builtin_amdgcn_s_waitcnt(0xC07F)  /* lgkmcnt<=0 */
#define BARRIER()    __builtin_amdgcn_s_barrier()

// adjacent-lane (xor 1) exchange-add via quad_perm [1,0,3,2]
__device__ __forceinline__ float dpp_addx1(float x) {
  int v = __builtin_amdgcn_update_dpp(0, __float_as_int(x), 0xB1, 0xF, 0xF, true);
  return x + __int_as_float(v);
}

// ---- all-weights transpose-convert + hs convert, ONE launch ----
__global__ __launch_bounds__(256) void tcvt_all_kernel(
    const float* __restrict__ Wq, const float* __restrict__ Wk,
    const float* __restrict__ Wv, const float* __restrict__ Wo,
    const float* __restrict__ hs,
    unsigned short* __restrict__ wqkvt, unsigned short* __restrict__ wot,
    unsigned short* __restrict__ hsb) {
  const int i = blockIdx.x;
  const int tx = threadIdx.x, ty = threadIdx.y;
  if (i >= 6144) {                           // hs convert: 1024 blocks x 4096 elems
    const int t = ty*32 + tx;
    const size_t base = (size_t)(i - 6144) * 1024;   // in float4 units
#pragma unroll
    for (int j = 0; j < 4; ++j) {
      const size_t idx = base + j*256 + t;
      float4 v = ((const float4*)hs)[idx];
      ushort4 o;
      o.x = f2bf(v.x); o.y = f2bf(v.y); o.z = f2bf(v.z); o.w = f2bf(v.w);
      ((ushort4*)hsb)[idx] = o;
    }
    return;
  }
  __shared__ float tl[32][33];
  const float* src; unsigned short* dst; int R, C, r0, c0;
  if (i < 2048)      { int l = i;        src = Wq; dst = wqkvt;                      R = 1024; C = 2048; r0 = (l & 31)*32; c0 = (l >> 5)*32; }
  else if (i < 3072) { int l = i - 2048; src = Wk; dst = wqkvt + (size_t)2048*1024;  R = 1024; C = 1024; r0 = (l & 31)*32; c0 = (l >> 5)*32; }
  else if (i < 4096) { int l = i - 3072; src = Wv; dst = wqkvt + (size_t)3072*1024;  R = 1024; C = 1024; r0 = (l & 31)*32; c0 = (l >> 5)*32; }
  else               { int l = i - 4096; src = Wo; dst = wot;                        R = 2048; C = 1024; r0 = (l & 63)*32; c0 = (l >> 6)*32; }
#pragma unroll
  for (int k = 0; k < 4; ++k)
    tl[ty + 8*k][tx] = src[(size_t)(r0 + ty + 8*k)*C + c0 + tx];
  __syncthreads();
#pragma unroll
  for (int k = 0; k < 4; ++k)
    dst[(size_t)(c0 + ty + 8*k)*R + r0 + tx] = f2bf(tl[tx][ty + 8*k]);
}

// -------- QKV GEMM (128x128, BK=64, async dbuf) + fused norm/rope/vtrans --------
// R12: vt8 written in kappa-permuted kv order so the attn PV B-fragment (P^T)
// needs NO cross-lane repack.
// R16: ftile stride 132 (epilogue now ~conflict-free).
// R18: K-loop LDS XOR-swizzle (T2, rule #21). Granule (m,kc) at m*8+kc has
// bank-group (kc&7)*4 independent of m -> 16-way conflict on every fragment
// ds_read_b128 (1.28e7 conflict cycles, the real source — FS fix was -4%).
// Fix: linear LDS dest + pre-swizzled global SOURCE (slot c fetches kchunk
// (c^(c>>3))&7) + swizzled READ (granule m*8 + (kc^(m&7))) -> 2-way (free).
__global__ __launch_bounds__(256) void gemm_qkv_fused_kernel(
    const unsigned short* __restrict__ A,      // hs bf16 [4096][1024]
    const unsigned short* __restrict__ Bt,     // wqkvt bf16 [4096][1024]
    const float* __restrict__ qw, const float* __restrict__ kw,
    const int* __restrict__ pos_ids,
    unsigned short* __restrict__ q_l,
    unsigned short* __restrict__ k_l,
    unsigned short* __restrict__ vt8) {
  constexpr int BM = 128, BK = 64, K = 1024, NIT = K/BK;
  constexpr int FS = 132;                      // ftile row stride (fp32 words)
  __shared__ __align__(16) char smem[70144];   // 68.5 KB -> 2 blocks/CU
  unsigned short* As0 = (unsigned short*)smem;           // 2 x 16 KB
  unsigned short* Bs0 = (unsigned short*)(smem + 32768); // 2 x 16 KB
  float* ftile = (float*)smem;                           // 128 x 132 fp32 (67.6 KB)
  float* rinv  = (float*)(smem + 69632);                 // 128 fp32

  const int t = threadIdx.x, lane = t & 63, w = t >> 6;
  const int l15 = lane & 15, l4 = lane >> 4;
  const int wr = (w >> 1)*64, wc = (w & 1)*64;
  const int m0 = blockIdx.x * BM, n0 = blockIdx.y * 128;
  const unsigned short* Ab = A + (size_t)m0*K;
  const unsigned short* Bb = Bt + (size_t)n0*K;

  const f32x4 vzero = {0.f, 0.f, 0.f, 0.f};
  f32x4 acc[4][4];
#pragma unroll
  for (int i = 0; i < 4; ++i)
#pragma unroll
    for (int j = 0; j < 4; ++j) acc[i][j] = vzero;

#pragma unroll
  for (int i = 0; i < 4; ++i) {
    const int c = (w*4 + i)*64 + lane;
    glds16(Ab + (size_t)(c >> 3)*K + ((c ^ (c >> 3)) & 7)*8, As0 + (size_t)(w*4 + i)*512);
  }
#pragma unroll
  for (int i = 0; i < 4; ++i) {
    const int c = (w*4 + i)*64 + lane;
    glds16(Bb + (size_t)(c >> 3)*K + ((c ^ (c >> 3)) & 7)*8, Bs0 + (size_t)(w*4 + i)*512);
  }

  for (int kb = 0; kb < NIT; ++kb) {
    const int cur = kb & 1;
    WAIT_LGKM0(); BARRIER();
    if (kb + 1 < NIT) {
      const int kn = (kb + 1) * BK;
      const int nb = (cur^1)*8192;
#pragma unroll
      for (int i = 0; i < 4; ++i) {
        const int c = (w*4 + i)*64 + lane;
        glds16(Ab + (size_t)(c >> 3)*K + kn + ((c ^ (c >> 3)) & 7)*8, As0 + nb + (size_t)(w*4 + i)*512);
      }
#pragma unroll
      for (int i = 0; i < 4; ++i) {
        const int c = (w*4 + i)*64 + lane;
        glds16(Bb + (size_t)(c >> 3)*K + kn + ((c ^ (c >> 3)) & 7)*8, Bs0 + nb + (size_t)(w*4 + i)*512);
      }
      WAIT_VM8();
    } else {
      WAIT_VM0();
    }
    BARRIER();

    const unsigned short* Ac = As0 + cur*8192;
    const unsigned short* Bc = Bs0 + cur*8192;
#pragma unroll
    for (int kk = 0; kk < 2; ++kk) {
      const int kc = kk*4 + l4;
      bf16x8 af[4], bfr[4];
#pragma unroll
      for (int i = 0; i < 4; ++i) {
        int m = wr + i*16 + l15;
        af[i] = *(const bf16x8*)(Ac + ((size_t)m*8 + (kc ^ (m & 7)))*8);
      }
#pragma unroll
      for (int j = 0; j < 4; ++j) {
        int n = wc + j*16 + l15;
        bfr[j] = *(const bf16x8*)(Bc + ((size_t)n*8 + (kc ^ (n & 7)))*8);
      }
#pragma unroll
      for (int i = 0; i < 4; ++i)
#pragma unroll
        for (int j = 0; j < 4; ++j)
          acc[i][j] = __builtin_amdgcn_mfma_f32_16x16x32_bf16(af[i], bfr[j], acc[i][j], 0, 0, 0);
    }
  }

  // ---- epilogue: spill C-tile to LDS fp32 [128][FS] ----
  WAIT_LGKM0(); BARRIER();
#pragma unroll
  for (int i = 0; i < 4; ++i)
#pragma unroll
    for (int j = 0; j < 4; ++j)
#pragma unroll
      for (int r = 0; r < 4; ++r) {
        const int row = wr + i*16 + l4*4 + r;
        const int col = wc + j*16 + l15;
        ftile[row*FS + col] = acc[i][j][r];
      }
  WAIT_LGKM0(); BARRIER();

  const int ny = n0 >> 7;                    // 0..15 q-head, 16..23 k-head, 24..31 v-head
  const int S0 = m0 & (SEQ-1);
  const int bb = m0 >> 11;

  if (ny < 24) {
    const bool isQ = ny < 16;
    {
      const int row = t >> 1, h2 = t & 1;
      const float* fr = ftile + row*FS + h2*64;
      float ssq = 0.f;
#pragma unroll
      for (int c = 0; c < 16; ++c) {
        float4 v = *(const float4*)(fr + 4*c);
        ssq += v.x*v.x + v.y*v.y + v.z*v.z + v.w*v.w;
      }
      ssq = dpp_addx1(ssq);
      if (h2 == 0) rinv[row] = rsqrtf(ssq*(1.0f/128.0f) + 1e-6f);
    }
    WAIT_LGKM0(); BARRIER();
    const float* wgt = isQ ? qw : kw;
    const int d = t & 127, rh = t >> 7;
    const float wd = wgt[d];
    const float w2 = wgt[d ^ 64];
    const float sgn = (d < 64) ? -1.f : 1.f;
    const float sOut = isQ ? 0.12751744f : 1.f;     // (1/sqrt(128))*log2(e) folded into q
    const float invf = exp2f(-(float)(d & 63) * 0.31143075889569023f);
    const int pos0 = pos_ids[S0 + rh*64];
    float cs, sn, dc, dsn;
    __sincosf((float)pos0 * invf, &sn, &cs);
    __sincosf(invf, &dsn, &dc);
    const int head = isQ ? ny : (ny - 16);
    unsigned short* dstb = isQ ? (q_l + ((size_t)(bb*NH + head)*SEQ + S0)*HD)
                               : (k_l + ((size_t)(bb*NKV + head)*SEQ + S0)*HD);
#pragma unroll 4
    for (int k = 0; k < 64; ++k) {
      const int row = rh*64 + k;
      const float r  = rinv[row];
      const float x1 = ftile[row*FS + d];
      const float x2 = ftile[row*FS + (d ^ 64)];
      const float y1 = x1*r*wd, y2 = x2*r*w2;
      const float o  = (y1*cs + sgn*(y2*sn)) * sOut;
      dstb[(size_t)row*HD + d] = f2bf(o);
      const float c2 = cs*dc - sn*dsn;       // rotate: pos -> pos+1
      sn = sn*dc + cs*dsn; cs = c2;
    }
  } else {
    // V-epilogue: kappa-permuted store. Slot (slice sl, elem s8) holds
    // C-row = blk*64 + s2*32 + e2*16 + s1*8 + s0*4 + e1*2 + e0.
    const int vh = ny - 24;
    unsigned short* vb = vt8 + (size_t)(bb*NKV + vh)*HD*SEQ;
    const int d = t & 127, sbh = t >> 7;
#pragma unroll
    for (int sb = 0; sb < 8; ++sb) {
      const int sl = sbh*8 + sb;
      const int blk = sl >> 3, s = sl & 7;
      const int base_r = blk*64 + ((s>>2)<<5) + (((s>>1)&1)<<3) + ((s&1)<<2);
      union { unsigned short u[8]; uint4 q; } pk;
#pragma unroll
      for (int s8 = 0; s8 < 8; ++s8) {
        const int row = base_r + ((s8>>2)<<4) + (((s8>>1)&1)<<1) + (s8&1);
        pk.u[s8] = f2bf(ftile[row*FS + d]);
      }
      *(uint4*)(vb + ((size_t)((S0 >> 3) + sl)*128 + d)*8) = pk.q;
    }
  }
}

// ------------- bf16 GEMM (out-proj): 128x128 tile, fp32 out -------------
// R18: same K-loop XOR-swizzle as gemm_qkv (pre-swizzled source + swizzled read).
__global__ __launch_bounds__(256) void gemm_out_kernel(
    const unsigned short* __restrict__ A,
    const unsigned short* __restrict__ Bt,
    float* __restrict__ Cout, int M, int N, int K) {
  constexpr int BK = 64;
  __shared__ unsigned short As[2][128*BK];   // 2 x 16 KB
  __shared__ unsigned short Bs[2][128*BK];   // 2 x 16 KB  -> 64 KB, 2 blocks/CU
  const int t = threadIdx.x, lane = t & 63, w = t >> 6;
  const int l15 = lane & 15, l4 = lane >> 4;
  const int wr = (w >> 1)*64, wc = (w & 1)*64;
  const int m0 = blockIdx.y * 128, n0 = blockIdx.x * 128;
  const unsigned short* Ab = A + (size_t)m0*K;
  const unsigned short* Bb = Bt + (size_t)n0*K;

  const f32x4 vzero = {0.f, 0.f, 0.f, 0.f};
  f32x4 acc[4][4];
#pragma unroll
  for (int i = 0; i < 4; ++i)
#pragma unroll
    for (int j = 0; j < 4; ++j) acc[i][j] = vzero;

  const int NIT = K / BK;
#pragma unroll
  for (int i = 0; i < 4; ++i) {
    const int c = (w*4 + i)*64 + lane;
    glds16(Ab + (size_t)(c >> 3)*K + ((c ^ (c >> 3)) & 7)*8, &As[0][(size_t)(w*4 + i)*512]);
  }
#pragma unroll
  for (int i = 0; i < 4; ++i) {
    const int c = (w*4 + i)*64 + lane;
    glds16(Bb + (size_t)(c >> 3)*K + ((c ^ (c >> 3)) & 7)*8, &Bs[0][(size_t)(w*4 + i)*512]);
  }

  for (int kb = 0; kb < NIT; ++kb) {
    const int cur = kb & 1;
    WAIT_LGKM0(); BARRIER();
    if (kb + 1 < NIT) {
      const int kn = (kb + 1) * BK;
#pragma unroll
      for (int i = 0; i < 4; ++i) {
        const int c = (w*4 + i)*64 + lane;
        glds16(Ab + (size_t)(c >> 3)*K + kn + ((c ^ (c >> 3)) & 7)*8, &As[cur^1][(size_t)(w*4 + i)*512]);
      }
#pragma unroll
      for (int i = 0; i < 4; ++i) {
        const int c = (w*4 + i)*64 + lane;
        glds16(Bb + (size_t)(c >> 3)*K + kn + ((c ^ (c >> 3)) & 7)*8, &Bs[cur^1][(size_t)(w*4 + i)*512]);
      }
      WAIT_VM8();
    } else {
      WAIT_VM0();
    }
    BARRIER();

#pragma unroll
    for (int kk = 0; kk < 2; ++kk) {
      const int kc = kk*4 + l4;
      bf16x8 af[4], bfr[4];
#pragma unroll
      for (int i = 0; i < 4; ++i) {
        int m = wr + i*16 + l15;
        af[i] = *(const bf16x8*)(&As[cur][((size_t)m*8 + (kc ^ (m & 7)))*8]);
      }
#pragma unroll
      for (int j = 0; j < 4; ++j) {
        int n = wc + j*16 + l15;
        bfr[j] = *(const bf16x8*)(&Bs[cur][((size_t)n*8 + (kc ^ (n & 7)))*8]);
      }
#pragma unroll
      for (int i = 0; i < 4; ++i)
#pragma unroll
        for (int j = 0; j < 4; ++j)
          acc[i][j] = __builtin_amdgcn_mfma_f32_16x16x32_bf16(af[i], bfr[j], acc[i][j], 0, 0, 0);
    }
  }
#pragma unroll
  for (int i = 0; i < 4; ++i)
#pragma unroll
    for (int j = 0; j < 4; ++j)
#pragma unroll
      for (int r = 0; r < 4; ++r) {
        int row = m0 + wr + i*16 + l4*4 + r;
        int col = n0 + wc + j*16 + l15;
        Cout[(size_t)row*N + col] = acc[i][j][r];
      }
}

// ------------- Flash attention, causal, GQA, KV-SPLIT -------------
// R14 memory config (proven: compulsory FETCH, 2 blocks/CU, dbuf K+V).
// R17 (verified: attn <60.1us, absmax 0.0234->0.0156): exp-split interleave +
// ones-MFMA row sums (oextra = mfma(ones, P) — denominator sums the SAME
// bf16-quantized P that feeds O).
__global__ __launch_bounds__(256, 2) void attn_kernel(
    const unsigned short* __restrict__ q_l,
    const unsigned short* __restrict__ k_l,
    const unsigned short* __restrict__ vt8,
    unsigned short* __restrict__ o_part,   // [2][B][NH][SEQ][HD] bf16
    float* __restrict__ l_part) {          // [2][B][NH][SEQ] fp32
  __shared__ __align__(16) char smem[65536];
  unsigned short* Ks0  = (unsigned short*)smem;            // 2 x 16 KB dbuf
  unsigned short* Vts0 = (unsigned short*)(smem + 32768);  // 2 x 16 KB dbuf

  const int t = threadIdx.x;
  const int lane = t & 63;
  const int w = t >> 6;
  const int l15 = lane & 15, l4 = lane >> 4;
  const int hb = blockIdx.x;                 // h + 16*b (fast dim: K/V L2 share)
  const int h = hb & 15, b = hb >> 4;
  const int y = blockIdx.y;                  // 0..31
  const int qt = 15 - (y >> 1);              // longest first
  const int half = y & 1;
  const int kvh = h >> 1;
  const int q0 = qt * 128;
  const int kt0 = half ? (qt + 1) : 0;
  const int kt1 = half ? (2*qt + 2) : (qt + 1);

  const unsigned short* Kg = k_l + ((size_t)(b*NKV + kvh)*SEQ)*HD;
  const unsigned short* Vg = vt8 + (size_t)(b*NKV + kvh)*HD*SEQ;
  const unsigned short* Qbase = q_l + ((size_t)(b*NH + h)*SEQ)*HD;

  const f32x4 vzero = {0.f,0.f,0.f,0.f};
  union { unsigned int u[4]; bf16x8 v; } vones;
#pragma unroll
  for (int i = 0; i < 4; ++i) vones.u[i] = 0x3F803F80u;   // bf16 1.0 x8

  // Q fragments in registers (already scaled by 1/sqrt(d)*log2e)
  bf16x8 qf[2][4];
#pragma unroll
  for (int i = 0; i < 2; ++i) {
    const int row = q0 + w*32 + i*16 + l15;
    const unsigned short* Qp = Qbase + (size_t)row*HD;
#pragma unroll
    for (int kk = 0; kk < 4; ++kk)
      qf[i][kk] = *(const bf16x8*)(Qp + kk*32 + l4*8);
  }

  f32x4 oacc[2][8];                          // O^T: [q-subtile][d-tile]
#pragma unroll
  for (int i = 0; i < 2; ++i)
#pragma unroll
    for (int jd = 0; jd < 8; ++jd) oacc[i][jd] = vzero;
  f32x4 oextra[2];                           // row-sum accumulator (ones-MFMA)
#pragma unroll
  for (int i = 0; i < 2; ++i) oextra[i] = vzero;

  // prologue: issue K(kt0)+V(kt0) into buf 0 (8 loads/wave, R1 pattern)
  {
    const int k00 = kt0 * 64;
#pragma unroll
    for (int i = 0; i < 4; ++i) {            // K tile
      const int kc = w*4 + i;
      const int m = lane ^ (kc & 7);
      glds16(Kg + (size_t)(k00 + m)*HD + kc*8, Ks0 + (size_t)kc*64*8);
    }
#pragma unroll
    for (int i = 0; i < 4; ++i) {            // V tile (kappa-permuted vt8)
      const int id = w*4 + i;
      const int skc = id >> 1, hh = id & 1;
      const int d = (hh*64 + lane) ^ skc;
      glds16(Vg + ((size_t)((k00 >> 3) + skc)*128 + d)*8, Vts0 + (size_t)(skc*128 + hh*64)*8);
    }
  }

#pragma unroll 1
  for (int kt = kt0; kt < kt1; ++kt) {
    const int cur = (kt - kt0) & 1;
    const int k0 = kt * 64;
    WAIT_LGKM0(); BARRIER();                 // all waves done reading buf cur^1
    if (kt + 1 < kt1) {                      // prefetch kt+1 into buf cur^1
      const int kn = k0 + 64;
      unsigned short* Ksn  = Ks0  + (cur^1)*8192;
      unsigned short* Vtsn = Vts0 + (cur^1)*8192;
#pragma unroll
      for (int i = 0; i < 4; ++i) {
        const int kc = w*4 + i;
        const int m = lane ^ (kc & 7);
        glds16(Kg + (size_t)(kn + m)*HD + kc*8, Ksn + (size_t)kc*64*8);
      }
#pragma unroll
      for (int i = 0; i < 4; ++i) {
        const int id = w*4 + i;
        const int skc = id >> 1, hh = id & 1;
        const int d = (hh*64 + lane) ^ skc;
        glds16(Vg + ((size_t)((kn >> 3) + skc)*128 + d)*8, Vtsn + (size_t)(skc*128 + hh*64)*8);
      }
      WAIT_VM8();                             // drain only cur's 8 loads
    } else {
      WAIT_VM0();
    }
    BARRIER();                                // buf cur fully staged

    const unsigned short* KsC  = Ks0  + cur*8192;
    const unsigned short* VtsC = Vts0 + cur*8192;

    // S^T = K Q^T (lane: q = l15 within subtile, kv = j*16 + l4*4 + r)
    f32x4 sacc[4][2];
#pragma unroll
    for (int j = 0; j < 4; ++j)
#pragma unroll
      for (int i = 0; i < 2; ++i) sacc[j][i] = vzero;
    __builtin_amdgcn_s_setprio(1);
#pragma unroll
    for (int kk = 0; kk < 4; ++kk) {
      const int kc = kk*4 + l4;
      bf16x8 kb[4];
#pragma unroll
      for (int j = 0; j < 4; ++j) {
        int n = j*16 + l15;
        kb[j] = *(const bf16x8*)(KsC + ((size_t)kc*64 + (n ^ (kc & 7)))*8);
      }
#pragma unroll
      for (int j = 0; j < 4; ++j)
#pragma unroll
        for (int i = 0; i < 2; ++i)
          sacc[j][i] = __builtin_amdgcn_mfma_f32_16x16x32_bf16(kb[j], qf[i][kk], sacc[j][i], 0,0,0);
    }
    __builtin_amdgcn_s_setprio(0);

    const bool diag = (kt >= 2*qt);
    // mask + exp2, j = 0,1 only (feeds PV kk=0)
#pragma unroll
    for (int j = 0; j < 2; ++j)
#pragma unroll
      for (int i = 0; i < 2; ++i)
#pragma unroll
        for (int r = 0; r < 4; ++r) {
          float sv = sacc[j][i][r];
          if (diag) {
            const int kvg = k0 + j*16 + l4*4 + r;
            const int qg  = q0 + w*32 + i*16 + l15;
            sv = (kvg > qg) ? -INFINITY : sv;
          }
          sacc[j][i][r] = EXP2(sv);
        }

    // PV kk=0 (uses sacc[0],[1]); j=2,3 exps issued right after the MFMA
    // cluster so they run on the trans pipe under PV0.
    {
      union { unsigned int u[4]; bf16x8 v; } pb[2];
#pragma unroll
      for (int i = 0; i < 2; ++i) {
        const f32x4 t0 = sacc[0][i], t1 = sacc[1][i];
        pb[i].u[0] = (__float_as_uint(t0[0]) >> 16) | (__float_as_uint(t0[1]) & 0xFFFF0000u);
        pb[i].u[1] = (__float_as_uint(t0[2]) >> 16) | (__float_as_uint(t0[3]) & 0xFFFF0000u);
        pb[i].u[2] = (__float_as_uint(t1[0]) >> 16) | (__float_as_uint(t1[1]) & 0xFFFF0000u);
        pb[i].u[3] = (__float_as_uint(t1[2]) >> 16) | (__float_as_uint(t1[3]) & 0xFFFF0000u);
      }
      const int s = l4;
      __builtin_amdgcn_s_setprio(1);
#pragma unroll
      for (int td = 0; td < 8; ++td) {
        const int dd = td*16 + l15;
        bf16x8 va = *(const bf16x8*)(VtsC + ((size_t)s*128 + (dd ^ s))*8);
#pragma unroll
        for (int i = 0; i < 2; ++i)
          oacc[i][td] = __builtin_amdgcn_mfma_f32_16x16x32_bf16(va, pb[i].v, oacc[i][td], 0,0,0);
      }
#pragma unroll
      for (int i = 0; i < 2; ++i)
        oextra[i] = __builtin_amdgcn_mfma_f32_16x16x32_bf16(vones.v, pb[i].v, oextra[i], 0,0,0);
      __builtin_amdgcn_s_setprio(0);

      // mask + exp2, j = 2,3 (overlaps PV0 on the trans pipe)
#pragma unroll
      for (int j = 2; j < 4; ++j)
#pragma unroll
        for (int i = 0; i < 2; ++i)
#pragma unroll
          for (int r = 0; r < 4; ++r) {
            float sv = sacc[j][i][r];
            if (diag) {
              const int kvg = k0 + j*16 + l4*4 + r;
              const int qg  = q0 + w*32 + i*16 + l15;
              sv = (kvg > qg) ? -INFINITY : sv;
            }
            sacc[j][i][r] = EXP2(sv);
          }
    }

    // PV kk=1 (uses sacc[2],[3])
    {
      union { unsigned int u[4]; bf16x8 v; } pb[2];
#pragma unroll
      for (int i = 0; i < 2; ++i) {
        const f32x4 t0 = sacc[2][i], t1 = sacc[3][i];
        pb[i].u[0] = (__float_as_uint(t0[0]) >> 16) | (__float_as_uint(t0[1]) & 0xFFFF0000u);
        pb[i].u[1] = (__float_as_uint(t0[2]) >> 16) | (__float_as_uint(t0[3]) & 0xFFFF0000u);
        pb[i].u[2] = (__float_as_uint(t1[0]) >> 16) | (__float_as_uint(t1[1]) & 0xFFFF0000u);
        pb[i].u[3] = (__float_as_uint(t1[2]) >> 16) | (__float_as_uint(t1[3]) & 0xFFFF0000u);
      }
      const int s = 4 + l4;
      __builtin_amdgcn_s_setprio(1);
#pragma unroll
      for (int td = 0; td < 8; ++td) {
        const int dd = td*16 + l15;
        bf16x8 va = *(const bf16x8*)(VtsC + ((size_t)s*128 + (dd ^ s))*8);
#pragma unroll
        for (int i = 0; i < 2; ++i)
          oacc[i][td] = __builtin_amdgcn_mfma_f32_16x16x32_bf16(va, pb[i].v, oacc[i][td], 0,0,0);
      }
#pragma unroll
      for (int i = 0; i < 2; ++i)
        oextra[i] = __builtin_amdgcn_mfma_f32_16x16x32_bf16(vones.v, pb[i].v, oextra[i], 0,0,0);
      __builtin_amdgcn_s_setprio(0);
    }
  }

  // epilogue: lane already holds the full row sum in oextra (all r equal);
  // normalize, store O^T. Fully-masked rows -> sum 0 -> store zeros.
  unsigned short* ob = o_part + ((size_t)half*BATCH*NH*SEQ + (size_t)(b*NH + h)*SEQ)*HD;
  float* lb = l_part + (size_t)half*BATCH*NH*SEQ + (size_t)(b*NH + h)*SEQ;
#pragma unroll
  for (int i = 0; i < 2; ++i) {
    const float lsum = oextra[i][0];
    const float inv = (lsum > 0.f) ? 1.0f / lsum : 0.f;
    const int row = q0 + w*32 + i*16 + l15;
    if (l4 == 0) lb[row] = lsum;
#pragma unroll
    for (int td = 0; td < 8; ++td) {
      union { unsigned int u[2]; uint2 q; } pk;
      const float v0 = oacc[i][td][0]*inv, v1 = oacc[i][td][1]*inv;
      const float v2 = oacc[i][td][2]*inv, v3 = oacc[i][td][3]*inv;
      pk.u[0] = (unsigned int)f2bf(v0) | ((unsigned int)f2bf(v1) << 16);
      pk.u[1] = (unsigned int)f2bf(v2) | ((unsigned int)f2bf(v3) << 16);
      *(uint2*)(ob + (size_t)row*HD + td*16 + l4*4) = pk.q;
    }
  }
}

// ------------- combine: attn_o = (la*Oa + lb*Ob) / (la+lb) -------------
__global__ __launch_bounds__(256) void combine_kernel(
    const unsigned short* __restrict__ o_part,  // [2][B*NH*SEQ][HD] bf16
    const float* __restrict__ l_part,           // [2][B*NH*SEQ] fp32
    unsigned short* __restrict__ attn_o) {      // [B][SEQ][NH*HD] bf16
  const int tid = blockIdx.x * 256 + threadIdx.x;  // 1,048,576 threads
  const int d8 = tid & 15;                    // 16 chunks of 8 d
  const int row = tid >> 4;                   // (b*NH+h)*SEQ + s
  const int s = row & (SEQ-1);
  const int bh = row >> 11;
  const int h = bh & 15, b = bh >> 4;
  const float la = l_part[row];
  const float lbv = l_part[BATCH*NH*SEQ + row];
  const float inv = 1.f / (la + lbv);
  const float wa = la * inv, wb = lbv * inv;
  const unsigned short* pa = o_part + (size_t)row*HD + d8*8;
  const unsigned short* pb = pa + (size_t)BATCH*NH*SEQ*HD;
  uint4 ua = *(const uint4*)pa;
  uint4 ub = *(const uint4*)pb;
  const unsigned short* ea = (const unsigned short*)&ua;
  const unsigned short* eb = (const unsigned short*)&ub;
  union { unsigned short u[8]; uint4 q; } o;
#pragma unroll
  for (int k = 0; k < 8; ++k)
    o.u[k] = f2bf(bf2f(ea[k])*wa + bf2f(eb[k])*wb);
  *(uint4*)(attn_o + ((size_t)(b*SEQ + s)*(NH*HD)) + h*HD + d8*8) = o.q;
}

extern "C" void kernel_launch(void* const* d_in, const int* in_sizes, int n_in,
                              void* d_out, int out_size, void* d_ws, size_t ws_size,
                              hipStream_t stream) {
  const float* hs = (const float*)d_in[0];
  const int* pos  = (const int*)d_in[1];
  const float* Wq = (const float*)d_in[2];
  const float* Wk = (const float*)d_in[3];
  const float* Wv = (const float*)d_in[4];
  const float* Wo = (const float*)d_in[5];
  const float* qw = (const float*)d_in[6];
  const float* kw = (const float*)d_in[7];
  float* out = (float*)d_out;
  char* ws = (char*)d_ws;

  unsigned short* attn_o = (unsigned short*)(ws + 0);                    // 16 MB
  unsigned short* wot    = (unsigned short*)(ws + ((size_t)16 << 20));   // 4 MB
  unsigned short* q_l    = (unsigned short*)(ws + ((size_t)20 << 20));   // 16 MB
  unsigned short* k_l    = (unsigned short*)(ws + ((size_t)36 << 20));   // 8 MB
  unsigned short* vt8    = (unsigned short*)(ws + ((size_t)44 << 20));   // 8 MB
  unsigned short* o_part = (unsigned short*)(ws + ((size_t)52 << 20));   // 32 MB
  unsigned short* hsb    = (unsigned short*)(ws + ((size_t)52 << 20));   // 8 MB (alias)
  unsigned short* wqkvt  = (unsigned short*)(ws + ((size_t)60 << 20));   // 8 MB (alias)
  float*          l_part = (float*)(ws + ((size_t)84 << 20));            // 512 KB

  // 1. all converts in one launch (weights transpose-convert + hs convert)
  tcvt_all_kernel<<<dim3(7168), dim3(32, 8), 0, stream>>>(Wq, Wk, Wv, Wo, hs, wqkvt, wot, hsb);
  // 2. QKV projection + fused RMSNorm/RoPE/V-transpose epilogue (kappa-permuted vt8)
  gemm_qkv_fused_kernel<<<dim3(32, 32), dim3(256), 0, stream>>>(hsb, wqkvt, qw, kw, pos, q_l, k_l, vt8);
  // 3. flash attention: R17 config (exp-split + ones-MFMA row sums)
  attn_kernel<<<dim3(32, 32), dim3(256), 0, stream>>>(q_l, k_l, vt8, o_part, l_part);
  // 3b. combine partials -> attn_o
  combine_kernel<<<dim3(4096), dim3(256), 0, stream>>>(o_part, l_part, attn_o);
  // 4. output projection: 128x128 tiles, grid (N/128=8, M/128=32) = 256 blocks
  gemm_out_kernel<<<dim3(8, 32), dim3(256), 0, stream>>>(attn_o, wot, out, 4096, 1024, 2048);
}